// Round 1
// baseline (7352.836 us; speedup 1.0000x reference)
//
#include <hip/hip_runtime.h>

typedef unsigned short u16;
typedef __attribute__((ext_vector_type(8))) __bf16 bf16x8;
typedef __attribute__((ext_vector_type(4))) float floatx4;

#define NTOK 1296      // P + H*(NO+NA) = 16 + 32*40
#define BN_TOT 10368   // B * NTOK
#define DMODEL 768
#define DFF 3072
#define NHEAD 12
#define DHEAD 64
#define NLAYER 12
#define SCALE_QK 0.125f  // 1/sqrt(64)

__device__ __forceinline__ u16 f2bf(float f) {
    unsigned u = __builtin_bit_cast(unsigned, f);
    unsigned r = (u + 0x7FFFu + ((u >> 16) & 1u)) >> 16;
    return (u16)r;
}

__device__ __forceinline__ float gelu_f(float x) {
    float u = 0.7978845608028654f * (x + 0.044715f * x * x * x);
    float t = 1.f - 2.f / (__expf(2.f * u) + 1.f);   // tanh(u)
    return 0.5f * x * (1.f + t);
}

__device__ __forceinline__ bool rule_ok(int i, int j) {
    if (j < 16) return true;
    if (i < 16) return false;
    int qi = i - 16, qj = j - 16;
    int ti = qi / 40, tj = qj / 40;
    int gi = ((qi % 40) < 32) ? 1 : 2;
    int gj = ((qj % 40) < 32) ? 1 : 2;
    if (gj == 1) return tj <= ti;
    return (gi == 2) && (tj <= ti);
}

// ---------------- input assembly ----------------
__global__ void assemble_x(const float* __restrict__ prefix,
                           const float* __restrict__ obs,
                           const float* __restrict__ act,
                           float* __restrict__ X) {
    int idx = blockIdx.x * 256 + threadIdx.x;
    if (idx >= BN_TOT * DMODEL) return;
    int d = idx % DMODEL;
    int n = (idx / DMODEL) % NTOK;
    int b = idx / (DMODEL * NTOK);
    float v;
    if (n < 16) {
        v = prefix[((size_t)b * 16 + n) * DMODEL + d];
    } else {
        int q = n - 16;
        int m = q / 40, r = q % 40;
        if (r < 32) v = obs[(((size_t)b * 32 + m) * 32 + r) * DMODEL + d];
        else        v = act[(((size_t)b * 32 + m) * 8 + (r - 32)) * DMODEL + d];
    }
    X[idx] = v;
}

__global__ void build_pad(const int* __restrict__ pm,
                          const int* __restrict__ om,
                          const int* __restrict__ am,
                          unsigned char* __restrict__ pad) {
    int idx = blockIdx.x * 256 + threadIdx.x;
    if (idx >= BN_TOT) return;
    int n = idx % NTOK, b = idx / NTOK;
    int v;
    if (n < 16) v = pm[b * 16 + n];
    else {
        int q = n - 16;
        int m = q / 40, r = q % 40;
        v = (r < 32) ? om[(b * 32 + m) * 32 + r] : am[(b * 32 + m) * 8 + (r - 32)];
    }
    pad[idx] = (v != 0) ? 1 : 0;
}

// ---------------- weight transpose + cvt: W fp32 [K][Nc] -> bf16 [Nc][K] ----------------
__global__ void transpose_cvt(const float* __restrict__ src, u16* __restrict__ dst,
                              int K, int Nc, long layerStride) {
    src += (size_t)blockIdx.z * K * Nc;
    dst += (size_t)blockIdx.z * layerStride;
    __shared__ float tile[32][33];
    int n0 = blockIdx.x * 32, k0 = blockIdx.y * 32;
    int tx = threadIdx.x, ty = threadIdx.y;
#pragma unroll
    for (int i = 0; i < 4; ++i)
        tile[ty + i * 8][tx] = src[(size_t)(k0 + ty + i * 8) * Nc + n0 + tx];
    __syncthreads();
#pragma unroll
    for (int i = 0; i < 4; ++i) {
        int n = n0 + ty + i * 8;
        dst[(size_t)n * K + k0 + tx] = f2bf(tile[tx][ty + i * 8]);
    }
}

// ---------------- LayerNorm ----------------
__global__ __launch_bounds__(256) void ln_kernel(const float* __restrict__ x,
                                                 const float* __restrict__ s,
                                                 const float* __restrict__ bb,
                                                 u16* __restrict__ obf,
                                                 float* __restrict__ of32) {
    int row = blockIdx.x;
    const float* xr = x + (size_t)row * DMODEL;
    int t = threadIdx.x;
    float v0 = xr[t], v1 = xr[t + 256], v2 = xr[t + 512];
    float sum = v0 + v1 + v2;
    float sq = v0 * v0 + v1 * v1 + v2 * v2;
#pragma unroll
    for (int d = 32; d > 0; d >>= 1) {
        sum += __shfl_down(sum, d);
        sq  += __shfl_down(sq, d);
    }
    __shared__ float ps[8], pq[8];
    int w = t >> 6, lane = t & 63;
    if (lane == 0) { ps[w] = sum; pq[w] = sq; }
    __syncthreads();
    if (t == 0) {
        float S = ps[0] + ps[1] + ps[2] + ps[3];
        float Q = pq[0] + pq[1] + pq[2] + pq[3];
        float mu = S * (1.f / DMODEL);
        float var = Q * (1.f / DMODEL) - mu * mu;
        ps[4] = mu; pq[4] = rsqrtf(var + 1e-6f);
    }
    __syncthreads();
    float mu = ps[4], rs = pq[4];
#pragma unroll
    for (int i = 0; i < 3; ++i) {
        int col = t + i * 256;
        float v = (i == 0 ? v0 : (i == 1 ? v1 : v2));
        float y = (v - mu) * rs * s[col] + bb[col];
        if (obf) obf[(size_t)row * DMODEL + col] = f2bf(y);
        else     of32[(size_t)row * DMODEL + col] = y;
    }
}

// ---------------- GEMM with global_load_lds staging + XOR-swizzled LDS ----------------
template <int EPI>
__global__ __launch_bounds__(256) void gemm_k(const u16* __restrict__ A,
                                              const u16* __restrict__ Bt,
                                              const float* __restrict__ bias,
                                              const float* __restrict__ resid,
                                              void* __restrict__ outp,
                                              int M, int Nc, int K) {
    __shared__ __attribute__((aligned(16))) u16 As[4096];  // 512 slots x 16B
    __shared__ __attribute__((aligned(16))) u16 Bs[4096];
    int tid = threadIdx.x;
    int bc = blockIdx.x, br = blockIdx.y;
    int lane = tid & 63, w = tid >> 6;
    int wr = (w >> 1) * 64, wc = (w & 1) * 64;
    int lr = lane & 15, C = lane >> 4;
    floatx4 acc[4][4] = {};

    int r0 = tid >> 2;       // staging row within 64-row half (0..63)
    int cph = tid & 3;       // physical 16B chunk slot within row
    const u16* Abase = A + (size_t)(br * 128) * K;
    const u16* Bbase = Bt + (size_t)(bc * 128) * K;

    for (int k0 = 0; k0 < K; k0 += 32) {
        __syncthreads();
#pragma unroll
        for (int i = 0; i < 2; ++i) {
            int r = i * 64 + r0;
            int cl = cph ^ ((r >> 1) & 3);
            const u16* ga = Abase + (size_t)r * K + k0 + cl * 8;
            const u16* gb = Bbase + (size_t)r * K + k0 + cl * 8;
            __builtin_amdgcn_global_load_lds(
                (const __attribute__((address_space(1))) void*)ga,
                (__attribute__((address_space(3))) void*)&As[(i * 256 + w * 64) * 8], 16, 0, 0);
            __builtin_amdgcn_global_load_lds(
                (const __attribute__((address_space(1))) void*)gb,
                (__attribute__((address_space(3))) void*)&Bs[(i * 256 + w * 64) * 8], 16, 0, 0);
        }
        __syncthreads();
        bf16x8 af[4], bf[4];
#pragma unroll
        for (int i = 0; i < 4; ++i) {
            int R = wr + i * 16 + lr;
            af[i] = *(const bf16x8*)&As[(R * 4 + (C ^ ((R >> 1) & 3))) * 8];
        }
#pragma unroll
        for (int i = 0; i < 4; ++i) {
            int R = wc + i * 16 + lr;
            bf[i] = *(const bf16x8*)&Bs[(R * 4 + (C ^ ((R >> 1) & 3))) * 8];
        }
#pragma unroll
        for (int i = 0; i < 4; ++i)
#pragma unroll
            for (int j = 0; j < 4; ++j)
                acc[i][j] = __builtin_amdgcn_mfma_f32_16x16x32_bf16(af[i], bf[j], acc[i][j], 0, 0, 0);
    }

    int gr0 = br * 128 + wr, gc0 = bc * 128 + wc;
#pragma unroll
    for (int i = 0; i < 4; ++i) {
#pragma unroll
        for (int j = 0; j < 4; ++j) {
#pragma unroll
            for (int r = 0; r < 4; ++r) {
                int grow = gr0 + i * 16 + (lane >> 4) * 4 + r;
                int gcol = gc0 + j * 16 + lr;
                float v = acc[i][j][r] + bias[gcol];
                if constexpr (EPI == 0) {
                    int b = grow / NTOK, n = grow % NTOK;
                    int nh = gcol >> 6, dh = gcol & 63;
                    ((u16*)outp)[(((size_t)b * NHEAD + nh) * NTOK + n) * DHEAD + dh] = f2bf(v);
                } else if constexpr (EPI == 1) {
                    int b = grow / NTOK, n = grow % NTOK;
                    int nh = gcol >> 6, dh = gcol & 63;
                    ((u16*)outp)[(((size_t)b * NHEAD + nh) * DHEAD + dh) * NTOK + n] = f2bf(v);
                } else if constexpr (EPI == 2) {
                    ((u16*)outp)[(size_t)grow * Nc + gcol] = f2bf(gelu_f(v));
                } else {
                    size_t idx = (size_t)grow * Nc + gcol;
                    ((float*)outp)[idx] = resid[idx] + v;
                }
            }
        }
    }
}

// ---------------- fused attention: barrier-free per-warp tiles, hoisted mask,
// causal sub-tile (ct) skip, scale folded into Q ----------------
__global__ __launch_bounds__(256) void attn_k(const u16* __restrict__ Q,
                                              const u16* __restrict__ Kb,
                                              const u16* __restrict__ Vt,
                                              const unsigned char* __restrict__ pad,
                                              u16* __restrict__ O) {
    // per-WARP P buffer: no cross-warp sharing -> no __syncthreads needed
    __shared__ __attribute__((aligned(16))) u16 plds[4][16 * 72];
    int qt = blockIdx.x, h = blockIdx.y, b = blockIdx.z;
    int tid = threadIdx.x, lane = tid & 63, w = tid >> 6;
    int rg = lane >> 4, lc = lane & 15;
    int q0 = qt * 64 + w * 16;
    size_t bh = (size_t)(b * NHEAD + h);

    int lastrow = min(qt * 64 + 63, NTOK - 1);
    int jend = (lastrow < 16) ? 16 : 16 + 40 * ((lastrow - 16) / 40 + 1);
    jend = min(jend, NTOK);
    int njt = (jend + 63) >> 6;

    // hoisted row (query) mask properties, loop-invariant
    int tmax_obs[4], tmax_act[4];
    bool rowok[4];
#pragma unroll
    for (int r = 0; r < 4; ++r) {
        int row = q0 + rg * 4 + r;
        rowok[r] = (row < NTOK);
        if (row >= 16 && row < NTOK) {
            int qi = row - 16;
            int ti = qi / 40;
            bool gact = (qi % 40) >= 32;
            tmax_obs[r] = ti;
            tmax_act[r] = gact ? ti : -1;
        } else {
            tmax_obs[r] = -1;   // prefix rows see prefix keys only
            tmax_act[r] = -1;
        }
    }

    // load Q fragment with 1/sqrt(DH) pre-folded (exact: *2^-3)
    const u16* qb = Q + (bh * NTOK + min(q0 + lc, NTOK - 1)) * DHEAD;
    bf16x8 qf0, qf1;
    {
        bf16x8 t0 = *(const bf16x8*)(qb + rg * 8);
        bf16x8 t1 = *(const bf16x8*)(qb + 32 + rg * 8);
#pragma unroll
        for (int i = 0; i < 8; ++i) {
            qf0[i] = (__bf16)((float)t0[i] * SCALE_QK);
            qf1[i] = (__bf16)((float)t1[i] * SCALE_QK);
        }
    }

    floatx4 oacc[4] = {};
    float mi[4] = {-3.0e38f, -3.0e38f, -3.0e38f, -3.0e38f};
    float li[4] = {0.f, 0.f, 0.f, 0.f};
    const unsigned char* padb = pad + (size_t)b * NTOK;

    for (int jt = 0; jt < njt; ++jt) {
        int j0 = jt * 64;
        int nct = min(4, (jend - j0 + 15) >> 4);   // valid 16-key sub-tiles
        floatx4 s[4];
#pragma unroll
        for (int ct = 0; ct < 4; ++ct) {
            if (ct < nct) {
                int key = j0 + ct * 16 + lc;
                int keyc = min(key, NTOK - 1);
                const u16* kb = Kb + (bh * NTOK + keyc) * DHEAD;
                bf16x8 kf0 = *(const bf16x8*)(kb + rg * 8);
                bf16x8 kf1 = *(const bf16x8*)(kb + 32 + rg * 8);
                floatx4 sa = {};
                sa = __builtin_amdgcn_mfma_f32_16x16x32_bf16(qf0, kf0, sa, 0, 0, 0);
                sa = __builtin_amdgcn_mfma_f32_16x16x32_bf16(qf1, kf1, sa, 0, 0, 0);
                s[ct] = sa;
            } else {
                s[ct] = (floatx4){-1.0e9f, -1.0e9f, -1.0e9f, -1.0e9f};
            }
        }
        // masking with hoisted row props; one division per valid ct
#pragma unroll
        for (int ct = 0; ct < 4; ++ct) {
            if (ct >= nct) continue;
            int col = j0 + ct * 16 + lc;
            bool colok = (col < jend) && (padb[min(col, NTOK - 1)] != 0);
            bool jpre = (col < 16);
            int tj = 0; bool jact = false;
            if (!jpre) { int qj = col - 16; tj = qj / 40; jact = (qj % 40) >= 32; }
#pragma unroll
            for (int r = 0; r < 4; ++r) {
                int tm = jact ? tmax_act[r] : tmax_obs[r];
                bool ok = colok && rowok[r] && (jpre || tj <= tm);
                s[ct][r] = ok ? s[ct][r] : -1.0e9f;
            }
        }
#pragma unroll
        for (int r = 0; r < 4; ++r) {
            float mx = fmaxf(fmaxf(s[0][r], s[1][r]), fmaxf(s[2][r], s[3][r]));
            mx = fmaxf(mx, __shfl_xor(mx, 1));
            mx = fmaxf(mx, __shfl_xor(mx, 2));
            mx = fmaxf(mx, __shfl_xor(mx, 4));
            mx = fmaxf(mx, __shfl_xor(mx, 8));
            float mnew = fmaxf(mi[r], mx);
            float alpha = __expf(mi[r] - mnew);
            float rs = 0.f;
#pragma unroll
            for (int ct = 0; ct < 4; ++ct) {
                float p = __expf(s[ct][r] - mnew);
                s[ct][r] = p;
                rs += p;
            }
            rs += __shfl_xor(rs, 1);
            rs += __shfl_xor(rs, 2);
            rs += __shfl_xor(rs, 4);
            rs += __shfl_xor(rs, 8);
            li[r] = li[r] * alpha + rs;
            mi[r] = mnew;
#pragma unroll
            for (int ct = 0; ct < 4; ++ct) oacc[ct][r] *= alpha;
        }
#pragma unroll
        for (int ct = 0; ct < 4; ++ct)
#pragma unroll
            for (int r = 0; r < 4; ++r)
                plds[w][(rg * 4 + r) * 72 + ct * 16 + lc] = f2bf(s[ct][r]);
        // intra-wave LDS exchange: program-order DS ops, no barrier needed
        bf16x8 pf0 = *(const bf16x8*)&plds[w][lc * 72 + rg * 8];
        bf16x8 pf1;
        if (nct > 2) pf1 = *(const bf16x8*)&plds[w][lc * 72 + 32 + rg * 8];
#pragma unroll
        for (int ct = 0; ct < 4; ++ct) {
            const u16* vb = Vt + (bh * DHEAD + ct * 16 + lc) * NTOK + j0;
            bf16x8 vf0 = *(const bf16x8*)(vb + rg * 8);
            oacc[ct] = __builtin_amdgcn_mfma_f32_16x16x32_bf16(pf0, vf0, oacc[ct], 0, 0, 0);
            if (nct > 2) {
                bf16x8 vf1 = *(const bf16x8*)(vb + 32 + rg * 8);
                oacc[ct] = __builtin_amdgcn_mfma_f32_16x16x32_bf16(pf1, vf1, oacc[ct], 0, 0, 0);
            }
        }
    }
#pragma unroll
    for (int r = 0; r < 4; ++r) {
        int row = q0 + rg * 4 + r;
        if (row < NTOK) {
            float inv = 1.f / li[r];
#pragma unroll
            for (int ct = 0; ct < 4; ++ct)
                O[((size_t)b * NTOK + row) * DMODEL + h * DHEAD + ct * 16 + lc] = f2bf(oacc[ct][r] * inv);
        }
    }
}

// ---------------- launcher ----------------
extern "C" void kernel_launch(void* const* d_in, const int* in_sizes, int n_in,
                              void* d_out, int out_size, void* d_ws, size_t ws_size,
                              hipStream_t stream) {
    const float* prefix = (const float*)d_in[0];
    const float* obs    = (const float*)d_in[1];
    const float* act    = (const float*)d_in[2];
    const float* ln1_s  = (const float*)d_in[3];
    const float* ln1_b  = (const float*)d_in[4];
    const float* ln2_s  = (const float*)d_in[5];
    const float* ln2_b  = (const float*)d_in[6];
    const float* wq = (const float*)d_in[7];
    const float* wk = (const float*)d_in[8];
    const float* wv = (const float*)d_in[9];
    const float* wo = (const float*)d_in[10];
    const float* bq = (const float*)d_in[11];
    const float* bk = (const float*)d_in[12];
    const float* bv = (const float*)d_in[13];
    const float* bo = (const float*)d_in[14];
    const float* w1 = (const float*)d_in[15];
    const float* b1 = (const float*)d_in[16];
    const float* w2 = (const float*)d_in[17];
    const float* b2 = (const float*)d_in[18];
    const float* lnf_s = (const float*)d_in[19];
    const float* lnf_b = (const float*)d_in[20];
    const int* pm = (const int*)d_in[21];
    const int* om = (const int*)d_in[22];
    const int* am = (const int*)d_in[23];
    float* out = (float*)d_out;

    char* ws = (char*)d_ws;
    size_t off = 0;
    auto carve = [&](size_t bytes) -> char* {
        char* p = ws + off;
        off += (bytes + 255) & ~(size_t)255;
        return p;
    };
    float* X   = (float*)carve((size_t)BN_TOT * DMODEL * 4);
    u16*   Hb  = (u16*)carve((size_t)BN_TOT * DMODEL * 2);
    u16*   Qb  = (u16*)carve((size_t)BN_TOT * DMODEL * 2);
    u16*   Kbf = (u16*)carve((size_t)BN_TOT * DMODEL * 2);
    u16*   Vt  = (u16*)carve((size_t)BN_TOT * DMODEL * 2 + 256);
    u16*   Ob  = (u16*)carve((size_t)BN_TOT * DMODEL * 2);
    u16*   MID = (u16*)carve((size_t)BN_TOT * DFF * 2);
    unsigned char* PAD = (unsigned char*)carve(BN_TOT);
    u16*   WT  = (u16*)carve((size_t)NLAYER * 7077888 * 2);
    if (off > ws_size) return;

    const long LSTR = 7077888;
    const long OWQ = 0, OWK = 589824, OWV = 1179648, OWO = 1769472, OW1 = 2359296, OW2 = 4718592;

    dim3 blk(256);
    assemble_x<<<(BN_TOT * DMODEL + 255) / 256, blk, 0, stream>>>(prefix, obs, act, X);
    build_pad<<<(BN_TOT + 255) / 256, blk, 0, stream>>>(pm, om, am, PAD);

    dim3 tb(32, 8);
    transpose_cvt<<<dim3(DMODEL / 32, DMODEL / 32, NLAYER), tb, 0, stream>>>(wq, WT + OWQ, DMODEL, DMODEL, LSTR);
    transpose_cvt<<<dim3(DMODEL / 32, DMODEL / 32, NLAYER), tb, 0, stream>>>(wk, WT + OWK, DMODEL, DMODEL, LSTR);
    transpose_cvt<<<dim3(DMODEL / 32, DMODEL / 32, NLAYER), tb, 0, stream>>>(wv, WT + OWV, DMODEL, DMODEL, LSTR);
    transpose_cvt<<<dim3(DMODEL / 32, DMODEL / 32, NLAYER), tb, 0, stream>>>(wo, WT + OWO, DMODEL, DMODEL, LSTR);
    transpose_cvt<<<dim3(DFF / 32, DMODEL / 32, NLAYER), tb, 0, stream>>>(w1, WT + OW1, DMODEL, DFF, LSTR);
    transpose_cvt<<<dim3(DMODEL / 32, DFF / 32, NLAYER), tb, 0, stream>>>(w2, WT + OW2, DFF, DMODEL, LSTR);

    dim3 g6(DMODEL / 128, BN_TOT / 128);
    dim3 g24(DFF / 128, BN_TOT / 128);
    dim3 ga(21, NHEAD, 8);

    for (int l = 0; l < NLAYER; ++l) {
        const u16* WTl = WT + (size_t)l * LSTR;
        ln_kernel<<<BN_TOT, blk, 0, stream>>>(X, ln1_s + l * DMODEL, ln1_b + l * DMODEL, Hb, nullptr);
        gemm_k<0><<<g6, blk, 0, stream>>>(Hb, WTl + OWQ, bq + l * DMODEL, nullptr, Qb, BN_TOT, DMODEL, DMODEL);
        gemm_k<0><<<g6, blk, 0, stream>>>(Hb, WTl + OWK, bk + l * DMODEL, nullptr, Kbf, BN_TOT, DMODEL, DMODEL);
        gemm_k<1><<<g6, blk, 0, stream>>>(Hb, WTl + OWV, bv + l * DMODEL, nullptr, Vt, BN_TOT, DMODEL, DMODEL);
        attn_k<<<ga, blk, 0, stream>>>(Qb, Kbf, Vt, PAD, Ob);
        gemm_k<3><<<g6, blk, 0, stream>>>(Ob, WTl + OWO, bo + l * DMODEL, X, X, BN_TOT, DMODEL, DMODEL);
        ln_kernel<<<BN_TOT, blk, 0, stream>>>(X, ln2_s + l * DMODEL, ln2_b + l * DMODEL, Hb, nullptr);
        gemm_k<2><<<g24, blk, 0, stream>>>(Hb, WTl + OW1, b1 + l * DFF, nullptr, MID, BN_TOT, DFF, DMODEL);
        gemm_k<3><<<g6, blk, 0, stream>>>(MID, WTl + OW2, b2 + l * DMODEL, X, X, BN_TOT, DMODEL, DFF);
    }
    ln_kernel<<<BN_TOT, blk, 0, stream>>>(X, lnf_s, lnf_b, nullptr, out);
}

// Round 2
// 6487.965 us; speedup vs baseline: 1.1333x; 1.1333x over previous
//
#include <hip/hip_runtime.h>

typedef unsigned short u16;
typedef __attribute__((ext_vector_type(8))) __bf16 bf16x8;
typedef __attribute__((ext_vector_type(4))) float floatx4;

#define NTOK 1296      // P + H*(NO+NA) = 16 + 32*40
#define BN_TOT 10368   // B * NTOK
#define DMODEL 768
#define DFF 3072
#define NHEAD 12
#define DHEAD 64
#define NLAYER 12
#define NQT 21         // ceil(NTOK/64)
#define SCALE_QK 0.125f  // 1/sqrt(64)

__device__ __forceinline__ u16 f2bf(float f) {
    unsigned u = __builtin_bit_cast(unsigned, f);
    unsigned r = (u + 0x7FFFu + ((u >> 16) & 1u)) >> 16;
    return (u16)r;
}

__device__ __forceinline__ float gelu_f(float x) {
    float u = 0.7978845608028654f * (x + 0.044715f * x * x * x);
    float t = 1.f - 2.f / (__expf(2.f * u) + 1.f);   // tanh(u)
    return 0.5f * x * (1.f + t);
}

// ---- DPP 16-lane butterfly reduce (VALU pipe, replaces ds_swizzle shuffles) ----
template <int CTRL>
__device__ __forceinline__ float dpp_f(float x) {
    int r = __builtin_amdgcn_update_dpp(0, __builtin_bit_cast(int, x), CTRL, 0xF, 0xF, true);
    return __builtin_bit_cast(float, r);
}
__device__ __forceinline__ float red16_max(float x) {
    x = fmaxf(x, dpp_f<0xB1>(x));    // quad_perm [1,0,3,2]  (xor 1)
    x = fmaxf(x, dpp_f<0x4E>(x));    // quad_perm [2,3,0,1]  (xor 2)
    x = fmaxf(x, dpp_f<0x141>(x));   // row_half_mirror      (pair quads 0-3 / 4-7)
    x = fmaxf(x, dpp_f<0x140>(x));   // row_mirror           (pair halves 0-7 / 8-15)
    return x;
}
__device__ __forceinline__ float red16_sum(float x) {
    x += dpp_f<0xB1>(x);
    x += dpp_f<0x4E>(x);
    x += dpp_f<0x141>(x);
    x += dpp_f<0x140>(x);
    return x;
}

// ---------------- input assembly ----------------
__global__ void assemble_x(const float* __restrict__ prefix,
                           const float* __restrict__ obs,
                           const float* __restrict__ act,
                           float* __restrict__ X) {
    int idx = blockIdx.x * 256 + threadIdx.x;
    if (idx >= BN_TOT * DMODEL) return;
    int d = idx % DMODEL;
    int n = (idx / DMODEL) % NTOK;
    int b = idx / (DMODEL * NTOK);
    float v;
    if (n < 16) {
        v = prefix[((size_t)b * 16 + n) * DMODEL + d];
    } else {
        int q = n - 16;
        int m = q / 40, r = q % 40;
        if (r < 32) v = obs[(((size_t)b * 32 + m) * 32 + r) * DMODEL + d];
        else        v = act[(((size_t)b * 32 + m) * 8 + (r - 32)) * DMODEL + d];
    }
    X[idx] = v;
}

__global__ void build_pad(const int* __restrict__ pm,
                          const int* __restrict__ om,
                          const int* __restrict__ am,
                          unsigned char* __restrict__ pad) {
    int idx = blockIdx.x * 256 + threadIdx.x;
    if (idx >= BN_TOT) return;
    int n = idx % NTOK, b = idx / NTOK;
    int v;
    if (n < 16) v = pm[b * 16 + n];
    else {
        int q = n - 16;
        int m = q / 40, r = q % 40;
        v = (r < 32) ? om[(b * 32 + m) * 32 + r] : am[(b * 32 + m) * 8 + (r - 32)];
    }
    pad[idx] = (v != 0) ? 1 : 0;
}

// ---------------- weight transpose + cvt: W fp32 [K][Nc] -> bf16 [Nc][K] ----------------
__global__ void transpose_cvt(const float* __restrict__ src, u16* __restrict__ dst,
                              int K, int Nc, long layerStride) {
    src += (size_t)blockIdx.z * K * Nc;
    dst += (size_t)blockIdx.z * layerStride;
    __shared__ float tile[32][33];
    int n0 = blockIdx.x * 32, k0 = blockIdx.y * 32;
    int tx = threadIdx.x, ty = threadIdx.y;
#pragma unroll
    for (int i = 0; i < 4; ++i)
        tile[ty + i * 8][tx] = src[(size_t)(k0 + ty + i * 8) * Nc + n0 + tx];
    __syncthreads();
#pragma unroll
    for (int i = 0; i < 4; ++i) {
        int n = n0 + ty + i * 8;
        dst[(size_t)n * K + k0 + tx] = f2bf(tile[tx][ty + i * 8]);
    }
}

// ---------------- LayerNorm ----------------
__global__ __launch_bounds__(256) void ln_kernel(const float* __restrict__ x,
                                                 const float* __restrict__ s,
                                                 const float* __restrict__ bb,
                                                 u16* __restrict__ obf,
                                                 float* __restrict__ of32) {
    int row = blockIdx.x;
    const float* xr = x + (size_t)row * DMODEL;
    int t = threadIdx.x;
    float v0 = xr[t], v1 = xr[t + 256], v2 = xr[t + 512];
    float sum = v0 + v1 + v2;
    float sq = v0 * v0 + v1 * v1 + v2 * v2;
#pragma unroll
    for (int d = 32; d > 0; d >>= 1) {
        sum += __shfl_down(sum, d);
        sq  += __shfl_down(sq, d);
    }
    __shared__ float ps[8], pq[8];
    int w = t >> 6, lane = t & 63;
    if (lane == 0) { ps[w] = sum; pq[w] = sq; }
    __syncthreads();
    if (t == 0) {
        float S = ps[0] + ps[1] + ps[2] + ps[3];
        float Q = pq[0] + pq[1] + pq[2] + pq[3];
        float mu = S * (1.f / DMODEL);
        float var = Q * (1.f / DMODEL) - mu * mu;
        ps[4] = mu; pq[4] = rsqrtf(var + 1e-6f);
    }
    __syncthreads();
    float mu = ps[4], rs = pq[4];
#pragma unroll
    for (int i = 0; i < 3; ++i) {
        int col = t + i * 256;
        float v = (i == 0 ? v0 : (i == 1 ? v1 : v2));
        float y = (v - mu) * rs * s[col] + bb[col];
        if (obf) obf[(size_t)row * DMODEL + col] = f2bf(y);
        else     of32[(size_t)row * DMODEL + col] = y;
    }
}

// ---------------- GEMM with global_load_lds staging + XOR-swizzled LDS ----------------
template <int EPI>
__global__ __launch_bounds__(256) void gemm_k(const u16* __restrict__ A,
                                              const u16* __restrict__ Bt,
                                              const float* __restrict__ bias,
                                              const float* __restrict__ resid,
                                              void* __restrict__ outp,
                                              int M, int Nc, int K) {
    __shared__ __attribute__((aligned(16))) u16 As[4096];  // 512 slots x 16B
    __shared__ __attribute__((aligned(16))) u16 Bs[4096];
    int tid = threadIdx.x;
    int bc = blockIdx.x, br = blockIdx.y;
    int lane = tid & 63, w = tid >> 6;
    int wr = (w >> 1) * 64, wc = (w & 1) * 64;
    int lr = lane & 15, C = lane >> 4;
    floatx4 acc[4][4] = {};

    int r0 = tid >> 2;       // staging row within 64-row half (0..63)
    int cph = tid & 3;       // physical 16B chunk slot within row
    const u16* Abase = A + (size_t)(br * 128) * K;
    const u16* Bbase = Bt + (size_t)(bc * 128) * K;

    for (int k0 = 0; k0 < K; k0 += 32) {
        __syncthreads();
#pragma unroll
        for (int i = 0; i < 2; ++i) {
            int r = i * 64 + r0;
            int cl = cph ^ ((r >> 1) & 3);
            const u16* ga = Abase + (size_t)r * K + k0 + cl * 8;
            const u16* gb = Bbase + (size_t)r * K + k0 + cl * 8;
            __builtin_amdgcn_global_load_lds(
                (const __attribute__((address_space(1))) void*)ga,
                (__attribute__((address_space(3))) void*)&As[(i * 256 + w * 64) * 8], 16, 0, 0);
            __builtin_amdgcn_global_load_lds(
                (const __attribute__((address_space(1))) void*)gb,
                (__attribute__((address_space(3))) void*)&Bs[(i * 256 + w * 64) * 8], 16, 0, 0);
        }
        __syncthreads();
        bf16x8 af[4], bf[4];
#pragma unroll
        for (int i = 0; i < 4; ++i) {
            int R = wr + i * 16 + lr;
            af[i] = *(const bf16x8*)&As[(R * 4 + (C ^ ((R >> 1) & 3))) * 8];
        }
#pragma unroll
        for (int i = 0; i < 4; ++i) {
            int R = wc + i * 16 + lr;
            bf[i] = *(const bf16x8*)&Bs[(R * 4 + (C ^ ((R >> 1) & 3))) * 8];
        }
#pragma unroll
        for (int i = 0; i < 4; ++i)
#pragma unroll
            for (int j = 0; j < 4; ++j)
                acc[i][j] = __builtin_amdgcn_mfma_f32_16x16x32_bf16(af[i], bf[j], acc[i][j], 0, 0, 0);
    }

    int gr0 = br * 128 + wr, gc0 = bc * 128 + wc;
#pragma unroll
    for (int i = 0; i < 4; ++i) {
#pragma unroll
        for (int j = 0; j < 4; ++j) {
#pragma unroll
            for (int r = 0; r < 4; ++r) {
                int grow = gr0 + i * 16 + (lane >> 4) * 4 + r;
                int gcol = gc0 + j * 16 + lr;
                float v = acc[i][j][r] + bias[gcol];
                if constexpr (EPI == 0) {
                    int b = grow / NTOK, n = grow % NTOK;
                    int nh = gcol >> 6, dh = gcol & 63;
                    ((u16*)outp)[(((size_t)b * NHEAD + nh) * NTOK + n) * DHEAD + dh] = f2bf(v);
                } else if constexpr (EPI == 1) {
                    int b = grow / NTOK, n = grow % NTOK;
                    int nh = gcol >> 6, dh = gcol & 63;
                    ((u16*)outp)[(((size_t)b * NHEAD + nh) * DHEAD + dh) * NTOK + n] = f2bf(v);
                } else if constexpr (EPI == 2) {
                    ((u16*)outp)[(size_t)grow * Nc + gcol] = f2bf(gelu_f(v));
                } else {
                    size_t idx = (size_t)grow * Nc + gcol;
                    ((float*)outp)[idx] = resid[idx] + v;
                }
            }
        }
    }
}

// ---------------- fused attention: straight-line loop, DPP softmax reduce,
// per-warp P tiles (barrier-free), XCD-grouped blocks ----------------
__global__ __launch_bounds__(256) void attn_k(const u16* __restrict__ Q,
                                              const u16* __restrict__ Kb,
                                              const u16* __restrict__ Vt,
                                              const unsigned char* __restrict__ pad,
                                              u16* __restrict__ O) {
    __shared__ __attribute__((aligned(16))) u16 plds[4][16 * 72];
    // XCD-grouped decode: all 21 qt-tiles of one (b,h) land on one XCD
    // wgid = ((g/8)*NQT + qt)*8 + (g%8), g = b*NHEAD + h
    int wgid = blockIdx.x;
    int xcd = wgid & 7, slot = wgid >> 3;
    int qt = slot % NQT;
    int g = (slot / NQT) * 8 + xcd;
    int b = g / NHEAD, h = g % NHEAD;

    int tid = threadIdx.x, lane = tid & 63, w = tid >> 6;
    int rg = lane >> 4, lc = lane & 15;
    int q0 = qt * 64 + w * 16;
    size_t bh = (size_t)(b * NHEAD + h);

    int lastrow = min(qt * 64 + 63, NTOK - 1);
    int jend = (lastrow < 16) ? 16 : 16 + 40 * ((lastrow - 16) / 40 + 1);
    jend = min(jend, NTOK);
    int njt = (jend + 63) >> 6;

    // hoisted row (query) mask properties, loop-invariant
    int tmax_obs[4], tmax_act[4];
    bool rowok[4];
#pragma unroll
    for (int r = 0; r < 4; ++r) {
        int row = q0 + rg * 4 + r;
        rowok[r] = (row < NTOK);
        if (row >= 16 && row < NTOK) {
            int qi = row - 16;
            int ti = qi / 40;
            bool gact = (qi % 40) >= 32;
            tmax_obs[r] = ti;
            tmax_act[r] = gact ? ti : -1;
        } else {
            tmax_obs[r] = -1;   // prefix rows see prefix keys only
            tmax_act[r] = -1;
        }
    }

    // load Q fragment with 1/sqrt(DH) pre-folded (exact: *2^-3)
    const u16* qb = Q + (bh * NTOK + min(q0 + lc, NTOK - 1)) * DHEAD;
    bf16x8 qf0, qf1;
    {
        bf16x8 t0 = *(const bf16x8*)(qb + rg * 8);
        bf16x8 t1 = *(const bf16x8*)(qb + 32 + rg * 8);
#pragma unroll
        for (int i = 0; i < 8; ++i) {
            qf0[i] = (__bf16)((float)t0[i] * SCALE_QK);
            qf1[i] = (__bf16)((float)t1[i] * SCALE_QK);
        }
    }

    floatx4 oacc[4] = {};
    float mi[4] = {-3.0e38f, -3.0e38f, -3.0e38f, -3.0e38f};
    float li[4] = {0.f, 0.f, 0.f, 0.f};
    const unsigned char* padb = pad + (size_t)b * NTOK;

    for (int jt = 0; jt < njt; ++jt) {
        int j0 = jt * 64;
        floatx4 s[4];
#pragma unroll
        for (int ct = 0; ct < 4; ++ct) {
            int keyc = min(j0 + ct * 16 + lc, NTOK - 1);
            const u16* kb = Kb + (bh * NTOK + keyc) * DHEAD;
            bf16x8 kf0 = *(const bf16x8*)(kb + rg * 8);
            bf16x8 kf1 = *(const bf16x8*)(kb + 32 + rg * 8);
            floatx4 sa = {};
            sa = __builtin_amdgcn_mfma_f32_16x16x32_bf16(qf0, kf0, sa, 0, 0, 0);
            sa = __builtin_amdgcn_mfma_f32_16x16x32_bf16(qf1, kf1, sa, 0, 0, 0);
            s[ct] = sa;
        }
        // masking with hoisted row props; one division per ct
#pragma unroll
        for (int ct = 0; ct < 4; ++ct) {
            int col = j0 + ct * 16 + lc;
            bool colok = (col < jend) && (padb[min(col, NTOK - 1)] != 0);
            bool jpre = (col < 16);
            int tj = 0; bool jact = false;
            if (!jpre) { int qj = col - 16; tj = qj / 40; jact = (qj % 40) >= 32; }
#pragma unroll
            for (int r = 0; r < 4; ++r) {
                int tm = jact ? tmax_act[r] : tmax_obs[r];
                bool ok = colok && rowok[r] && (jpre || tj <= tm);
                s[ct][r] = ok ? s[ct][r] : -1.0e9f;
            }
        }
        // online softmax with DPP reduces (VALU pipe, no DS latency)
#pragma unroll
        for (int r = 0; r < 4; ++r) {
            float mx = fmaxf(fmaxf(s[0][r], s[1][r]), fmaxf(s[2][r], s[3][r]));
            mx = red16_max(mx);
            float mnew = fmaxf(mi[r], mx);
            float alpha = __expf(mi[r] - mnew);
            float rs = 0.f;
#pragma unroll
            for (int ct = 0; ct < 4; ++ct) {
                float p = __expf(s[ct][r] - mnew);
                s[ct][r] = p;
                rs += p;
            }
            rs = red16_sum(rs);
            li[r] = li[r] * alpha + rs;
            mi[r] = mnew;
#pragma unroll
            for (int ct = 0; ct < 4; ++ct) oacc[ct][r] *= alpha;
        }
#pragma unroll
        for (int ct = 0; ct < 4; ++ct)
#pragma unroll
            for (int r = 0; r < 4; ++r)
                plds[w][(rg * 4 + r) * 72 + ct * 16 + lc] = f2bf(s[ct][r]);
        // intra-wave LDS exchange: program-order DS ops, no barrier needed
        bf16x8 pf0 = *(const bf16x8*)&plds[w][lc * 72 + rg * 8];
        bf16x8 pf1 = *(const bf16x8*)&plds[w][lc * 72 + 32 + rg * 8];
#pragma unroll
        for (int ct = 0; ct < 4; ++ct) {
            const u16* vb = Vt + (bh * DHEAD + ct * 16 + lc) * NTOK + j0;
            bf16x8 vf0 = *(const bf16x8*)(vb + rg * 8);
            bf16x8 vf1 = *(const bf16x8*)(vb + 32 + rg * 8);
            oacc[ct] = __builtin_amdgcn_mfma_f32_16x16x32_bf16(pf0, vf0, oacc[ct], 0, 0, 0);
            oacc[ct] = __builtin_amdgcn_mfma_f32_16x16x32_bf16(pf1, vf1, oacc[ct], 0, 0, 0);
        }
    }
#pragma unroll
    for (int r = 0; r < 4; ++r) {
        int row = q0 + rg * 4 + r;
        if (row < NTOK) {
            float inv = 1.f / li[r];
#pragma unroll
            for (int ct = 0; ct < 4; ++ct)
                O[((size_t)b * NTOK + row) * DMODEL + h * DHEAD + ct * 16 + lc] = f2bf(oacc[ct][r] * inv);
        }
    }
}

// ---------------- launcher ----------------
extern "C" void kernel_launch(void* const* d_in, const int* in_sizes, int n_in,
                              void* d_out, int out_size, void* d_ws, size_t ws_size,
                              hipStream_t stream) {
    const float* prefix = (const float*)d_in[0];
    const float* obs    = (const float*)d_in[1];
    const float* act    = (const float*)d_in[2];
    const float* ln1_s  = (const float*)d_in[3];
    const float* ln1_b  = (const float*)d_in[4];
    const float* ln2_s  = (const float*)d_in[5];
    const float* ln2_b  = (const float*)d_in[6];
    const float* wq = (const float*)d_in[7];
    const float* wk = (const float*)d_in[8];
    const float* wv = (const float*)d_in[9];
    const float* wo = (const float*)d_in[10];
    const float* bq = (const float*)d_in[11];
    const float* bk = (const float*)d_in[12];
    const float* bv = (const float*)d_in[13];
    const float* bo = (const float*)d_in[14];
    const float* w1 = (const float*)d_in[15];
    const float* b1 = (const float*)d_in[16];
    const float* w2 = (const float*)d_in[17];
    const float* b2 = (const float*)d_in[18];
    const float* lnf_s = (const float*)d_in[19];
    const float* lnf_b = (const float*)d_in[20];
    const int* pm = (const int*)d_in[21];
    const int* om = (const int*)d_in[22];
    const int* am = (const int*)d_in[23];
    float* out = (float*)d_out;

    char* ws = (char*)d_ws;
    size_t off = 0;
    auto carve = [&](size_t bytes) -> char* {
        char* p = ws + off;
        off += (bytes + 255) & ~(size_t)255;
        return p;
    };
    float* X   = (float*)carve((size_t)BN_TOT * DMODEL * 4);
    u16*   Hb  = (u16*)carve((size_t)BN_TOT * DMODEL * 2);
    u16*   Qb  = (u16*)carve((size_t)BN_TOT * DMODEL * 2);
    u16*   Kbf = (u16*)carve((size_t)BN_TOT * DMODEL * 2);
    u16*   Vt  = (u16*)carve((size_t)BN_TOT * DMODEL * 2 + 256);
    u16*   Ob  = (u16*)carve((size_t)BN_TOT * DMODEL * 2);
    u16*   MID = (u16*)carve((size_t)BN_TOT * DFF * 2);
    unsigned char* PAD = (unsigned char*)carve(BN_TOT);
    u16*   WT  = (u16*)carve((size_t)NLAYER * 7077888 * 2);
    if (off > ws_size) return;

    const long LSTR = 7077888;
    const long OWQ = 0, OWK = 589824, OWV = 1179648, OWO = 1769472, OW1 = 2359296, OW2 = 4718592;

    dim3 blk(256);
    assemble_x<<<(BN_TOT * DMODEL + 255) / 256, blk, 0, stream>>>(prefix, obs, act, X);
    build_pad<<<(BN_TOT + 255) / 256, blk, 0, stream>>>(pm, om, am, PAD);

    dim3 tb(32, 8);
    transpose_cvt<<<dim3(DMODEL / 32, DMODEL / 32, NLAYER), tb, 0, stream>>>(wq, WT + OWQ, DMODEL, DMODEL, LSTR);
    transpose_cvt<<<dim3(DMODEL / 32, DMODEL / 32, NLAYER), tb, 0, stream>>>(wk, WT + OWK, DMODEL, DMODEL, LSTR);
    transpose_cvt<<<dim3(DMODEL / 32, DMODEL / 32, NLAYER), tb, 0, stream>>>(wv, WT + OWV, DMODEL, DMODEL, LSTR);
    transpose_cvt<<<dim3(DMODEL / 32, DMODEL / 32, NLAYER), tb, 0, stream>>>(wo, WT + OWO, DMODEL, DMODEL, LSTR);
    transpose_cvt<<<dim3(DFF / 32, DMODEL / 32, NLAYER), tb, 0, stream>>>(w1, WT + OW1, DMODEL, DFF, LSTR);
    transpose_cvt<<<dim3(DMODEL / 32, DFF / 32, NLAYER), tb, 0, stream>>>(w2, WT + OW2, DFF, DMODEL, LSTR);

    dim3 g6(DMODEL / 128, BN_TOT / 128);
    dim3 g24(DFF / 128, BN_TOT / 128);
    dim3 ga(NQT * NHEAD * 8);   // 2016, XCD-grouped decode inside kernel

    for (int l = 0; l < NLAYER; ++l) {
        const u16* WTl = WT + (size_t)l * LSTR;
        ln_kernel<<<BN_TOT, blk, 0, stream>>>(X, ln1_s + l * DMODEL, ln1_b + l * DMODEL, Hb, nullptr);
        gemm_k<0><<<g6, blk, 0, stream>>>(Hb, WTl + OWQ, bq + l * DMODEL, nullptr, Qb, BN_TOT, DMODEL, DMODEL);
        gemm_k<0><<<g6, blk, 0, stream>>>(Hb, WTl + OWK, bk + l * DMODEL, nullptr, Kbf, BN_TOT, DMODEL, DMODEL);
        gemm_k<1><<<g6, blk, 0, stream>>>(Hb, WTl + OWV, bv + l * DMODEL, nullptr, Vt, BN_TOT, DMODEL, DMODEL);
        attn_k<<<ga, blk, 0, stream>>>(Qb, Kbf, Vt, PAD, Ob);
        gemm_k<3><<<g6, blk, 0, stream>>>(Ob, WTl + OWO, bo + l * DMODEL, X, X, BN_TOT, DMODEL, DMODEL);
        ln_kernel<<<BN_TOT, blk, 0, stream>>>(X, ln2_s + l * DMODEL, ln2_b + l * DMODEL, Hb, nullptr);
        gemm_k<2><<<g24, blk, 0, stream>>>(Hb, WTl + OW1, b1 + l * DFF, nullptr, MID, BN_TOT, DFF, DMODEL);
        gemm_k<3><<<g6, blk, 0, stream>>>(MID, WTl + OW2, b2 + l * DMODEL, X, X, BN_TOT, DMODEL, DFF);
    }
    ln_kernel<<<BN_TOT, blk, 0, stream>>>(X, lnf_s, lnf_b, nullptr, out);
}

// Round 3
// 6312.681 us; speedup vs baseline: 1.1648x; 1.0278x over previous
//
#include <hip/hip_runtime.h>

typedef unsigned short u16;
typedef __attribute__((ext_vector_type(8))) __bf16 bf16x8;
typedef __attribute__((ext_vector_type(4))) float floatx4;

#define NTOK 1296      // P + H*(NO+NA) = 16 + 32*40
#define BN_TOT 10368   // B * NTOK
#define DMODEL 768
#define DFF 3072
#define NHEAD 12
#define DHEAD 64
#define NLAYER 12
#define NQT 21         // ceil(NTOK/64)
#define SCALE_QK 0.125f  // 1/sqrt(64)

__device__ __forceinline__ u16 f2bf(float f) {
    unsigned u = __builtin_bit_cast(unsigned, f);
    unsigned r = (u + 0x7FFFu + ((u >> 16) & 1u)) >> 16;
    return (u16)r;
}

__device__ __forceinline__ unsigned cvt_pk_bf16(float lo, float hi) {
    unsigned r;
    asm("v_cvt_pk_bf16_f32 %0, %1, %2" : "=v"(r) : "v"(lo), "v"(hi));
    return r;
}

__device__ __forceinline__ float gelu_f(float x) {
    float u = 0.7978845608028654f * (x + 0.044715f * x * x * x);
    float t = 1.f - 2.f / (__expf(2.f * u) + 1.f);   // tanh(u)
    return 0.5f * x * (1.f + t);
}

// ---------------- input assembly ----------------
__global__ void assemble_x(const float* __restrict__ prefix,
                           const float* __restrict__ obs,
                           const float* __restrict__ act,
                           float* __restrict__ X) {
    int idx = blockIdx.x * 256 + threadIdx.x;
    if (idx >= BN_TOT * DMODEL) return;
    int d = idx % DMODEL;
    int n = (idx / DMODEL) % NTOK;
    int b = idx / (DMODEL * NTOK);
    float v;
    if (n < 16) {
        v = prefix[((size_t)b * 16 + n) * DMODEL + d];
    } else {
        int q = n - 16;
        int m = q / 40, r = q % 40;
        if (r < 32) v = obs[(((size_t)b * 32 + m) * 32 + r) * DMODEL + d];
        else        v = act[(((size_t)b * 32 + m) * 8 + (r - 32)) * DMODEL + d];
    }
    X[idx] = v;
}

__global__ void build_pad(const int* __restrict__ pm,
                          const int* __restrict__ om,
                          const int* __restrict__ am,
                          unsigned char* __restrict__ pad) {
    int idx = blockIdx.x * 256 + threadIdx.x;
    if (idx >= BN_TOT) return;
    int n = idx % NTOK, b = idx / NTOK;
    int v;
    if (n < 16) v = pm[b * 16 + n];
    else {
        int q = n - 16;
        int m = q / 40, r = q % 40;
        v = (r < 32) ? om[(b * 32 + m) * 32 + r] : am[(b * 32 + m) * 8 + (r - 32)];
    }
    pad[idx] = (v != 0) ? 1 : 0;
}

__global__ void build_biascat(const float* __restrict__ bq,
                              const float* __restrict__ bk,
                              const float* __restrict__ bv,
                              float* __restrict__ bc) {
    int idx = blockIdx.x * 256 + threadIdx.x;
    if (idx >= NLAYER * 2304) return;
    int l = idx / 2304, c = idx % 2304;
    int which = c / 768, cc = c % 768;
    const float* src = (which == 0) ? bq : (which == 1) ? bk : bv;
    bc[idx] = src[l * 768 + cc];
}

// ---------------- weight transpose + cvt: W fp32 [K][Nc] -> bf16 [Nc][K] ----------------
__global__ void transpose_cvt(const float* __restrict__ src, u16* __restrict__ dst,
                              int K, int Nc, long layerStride) {
    src += (size_t)blockIdx.z * K * Nc;
    dst += (size_t)blockIdx.z * layerStride;
    __shared__ float tile[32][33];
    int n0 = blockIdx.x * 32, k0 = blockIdx.y * 32;
    int tx = threadIdx.x, ty = threadIdx.y;
#pragma unroll
    for (int i = 0; i < 4; ++i)
        tile[ty + i * 8][tx] = src[(size_t)(k0 + ty + i * 8) * Nc + n0 + tx];
    __syncthreads();
#pragma unroll
    for (int i = 0; i < 4; ++i) {
        int n = n0 + ty + i * 8;
        dst[(size_t)n * K + k0 + tx] = f2bf(tile[tx][ty + i * 8]);
    }
}

// ---------------- LayerNorm: one wave per row, no barriers ----------------
__global__ __launch_bounds__(256) void ln_kernel(const float* __restrict__ x,
                                                 const float* __restrict__ s,
                                                 const float* __restrict__ bb,
                                                 u16* __restrict__ obf,
                                                 float* __restrict__ of32) {
    int row = blockIdx.x * 4 + (threadIdx.x >> 6);
    int lane = threadIdx.x & 63;
    const float4* xv = (const float4*)(x + (size_t)row * DMODEL);
    float4 v[3];
    v[0] = xv[lane]; v[1] = xv[lane + 64]; v[2] = xv[lane + 128];
    float sum = 0.f, sq = 0.f;
#pragma unroll
    for (int i = 0; i < 3; ++i) {
        sum += v[i].x + v[i].y + v[i].z + v[i].w;
        sq  += v[i].x * v[i].x + v[i].y * v[i].y + v[i].z * v[i].z + v[i].w * v[i].w;
    }
#pragma unroll
    for (int d = 32; d > 0; d >>= 1) {
        sum += __shfl_xor(sum, d);
        sq  += __shfl_xor(sq, d);
    }
    float mu = sum * (1.f / DMODEL);
    float var = sq * (1.f / DMODEL) - mu * mu;
    float rstd = rsqrtf(var + 1e-6f);
    const float4* sv = (const float4*)s;
    const float4* bv = (const float4*)bb;
#pragma unroll
    for (int i = 0; i < 3; ++i) {
        float4 sc = sv[lane + i * 64], bc = bv[lane + i * 64];
        float y0 = (v[i].x - mu) * rstd * sc.x + bc.x;
        float y1 = (v[i].y - mu) * rstd * sc.y + bc.y;
        float y2 = (v[i].z - mu) * rstd * sc.z + bc.z;
        float y3 = (v[i].w - mu) * rstd * sc.w + bc.w;
        size_t base = (size_t)row * DMODEL + i * 256 + lane * 4;
        if (obf) {
            uint2 pk;
            pk.x = (unsigned)f2bf(y0) | ((unsigned)f2bf(y1) << 16);
            pk.y = (unsigned)f2bf(y2) | ((unsigned)f2bf(y3) << 16);
            *(uint2*)&obf[base] = pk;
        } else {
            float4 o = {y0, y1, y2, y3};
            *(float4*)&of32[base] = o;
        }
    }
}

// ---------------- GEMM with global_load_lds staging + XOR-swizzled LDS ----------------
template <int EPI>
__global__ __launch_bounds__(256) void gemm_k(const u16* __restrict__ A,
                                              const u16* __restrict__ Bt,
                                              const float* __restrict__ bias,
                                              const float* __restrict__ resid,
                                              void* __restrict__ outp,
                                              int M, int Nc, int K) {
    __shared__ __attribute__((aligned(16))) u16 As[4096];  // 512 slots x 16B
    __shared__ __attribute__((aligned(16))) u16 Bs[4096];
    int tid = threadIdx.x;
    int bc = blockIdx.x, br = blockIdx.y;
    int lane = tid & 63, w = tid >> 6;
    int wr = (w >> 1) * 64, wc = (w & 1) * 64;
    int lr = lane & 15, C = lane >> 4;
    floatx4 acc[4][4] = {};

    int r0 = tid >> 2;       // staging row within 64-row half (0..63)
    int cph = tid & 3;       // physical 16B chunk slot within row
    const u16* Abase = A + (size_t)(br * 128) * K;
    const u16* Bbase = Bt + (size_t)(bc * 128) * K;

    for (int k0 = 0; k0 < K; k0 += 32) {
        __syncthreads();
#pragma unroll
        for (int i = 0; i < 2; ++i) {
            int r = i * 64 + r0;
            int cl = cph ^ ((r >> 1) & 3);
            const u16* ga = Abase + (size_t)r * K + k0 + cl * 8;
            const u16* gb = Bbase + (size_t)r * K + k0 + cl * 8;
            __builtin_amdgcn_global_load_lds(
                (const __attribute__((address_space(1))) void*)ga,
                (__attribute__((address_space(3))) void*)&As[(i * 256 + w * 64) * 8], 16, 0, 0);
            __builtin_amdgcn_global_load_lds(
                (const __attribute__((address_space(1))) void*)gb,
                (__attribute__((address_space(3))) void*)&Bs[(i * 256 + w * 64) * 8], 16, 0, 0);
        }
        __syncthreads();
        bf16x8 af[4], bf[4];
#pragma unroll
        for (int i = 0; i < 4; ++i) {
            int R = wr + i * 16 + lr;
            af[i] = *(const bf16x8*)&As[(R * 4 + (C ^ ((R >> 1) & 3))) * 8];
        }
#pragma unroll
        for (int i = 0; i < 4; ++i) {
            int R = wc + i * 16 + lr;
            bf[i] = *(const bf16x8*)&Bs[(R * 4 + (C ^ ((R >> 1) & 3))) * 8];
        }
#pragma unroll
        for (int i = 0; i < 4; ++i)
#pragma unroll
            for (int j = 0; j < 4; ++j)
                acc[i][j] = __builtin_amdgcn_mfma_f32_16x16x32_bf16(af[i], bf[j], acc[i][j], 0, 0, 0);
    }

    int gr0 = br * 128 + wr, gc0 = bc * 128 + wc;
#pragma unroll
    for (int i = 0; i < 4; ++i) {
#pragma unroll
        for (int j = 0; j < 4; ++j) {
#pragma unroll
            for (int r = 0; r < 4; ++r) {
                int grow = gr0 + i * 16 + (lane >> 4) * 4 + r;
                int gcol = gc0 + j * 16 + lr;
                float v = acc[i][j][r] + bias[gcol];
                if constexpr (EPI == 2) {
                    ((u16*)outp)[(size_t)grow * Nc + gcol] = f2bf(gelu_f(v));
                } else if constexpr (EPI == 3) {
                    size_t idx = (size_t)grow * Nc + gcol;
                    ((float*)outp)[idx] = resid[idx] + v;
                } else {  // EPI == 4: fused QKV epilogue; outp = Qb (K,V at fixed offsets)
                    int b = grow / NTOK, n = grow % NTOK;
                    int which = gcol / 768;
                    int c = gcol - which * 768;
                    int nh = c >> 6, dh = c & 63;
                    u16* base = (u16*)outp + (size_t)which * ((size_t)BN_TOT * DMODEL);
                    if (which < 2)
                        base[(((size_t)b * NHEAD + nh) * NTOK + n) * DHEAD + dh] = f2bf(v);
                    else
                        base[(((size_t)b * NHEAD + nh) * DHEAD + dh) * NTOK + n] = f2bf(v);
                }
            }
        }
    }
}

// ---------------- fused attention: swapped-operand S^T, per-lane softmax,
// packed XOR-swizzled P-LDS, O^T PV, XCD-grouped + longest-first ----------------
__global__ __launch_bounds__(256) void attn_k(const u16* __restrict__ Q,
                                              const u16* __restrict__ Kb,
                                              const u16* __restrict__ Vt,
                                              const unsigned char* __restrict__ pad,
                                              u16* __restrict__ O) {
    // per-warp P tile: 16 q-rows x 64 keys bf16, row stride 64 u16 (128B),
    // chunk(16B)-XOR swizzle by (row&7) -> conflict-free writes, minimal reads
    __shared__ __attribute__((aligned(16))) u16 plds[4][16 * 64];
    int wgid = blockIdx.x;
    int xcd = wgid & 7, slot = wgid >> 3;
    int qt = NQT - 1 - (slot % NQT);          // longest q-tiles dispatch first
    int g = (slot / NQT) * 8 + xcd;           // all 21 tiles of (b,h) on one XCD
    int b = g / NHEAD, h = g % NHEAD;

    int tid = threadIdx.x, lane = tid & 63, w = tid >> 6;
    int rg = lane >> 4, lc = lane & 15;
    int q0 = qt * 64 + w * 16;
    size_t bh = (size_t)(b * NHEAD + h);

    int lastrow = min(qt * 64 + 63, NTOK - 1);
    int jend = (lastrow < 16) ? 16 : 16 + 40 * ((lastrow - 16) / 40 + 1);
    jend = min(jend, NTOK);
    int njt = (jend + 63) >> 6;

    int q = q0 + lc;                 // this lane's query row (col of S^T)
    bool qok = q < NTOK;
    int tmax_obs = -1, tmax_act = -1;
    if (qok && q >= 16) {
        int qi = q - 16;
        int ti = qi / 40;
        bool gact = (qi % 40) >= 32;
        tmax_obs = ti;
        tmax_act = gact ? ti : -1;
    }

    // Q fragment (B operand), 1/sqrt(DH) pre-folded (exact *2^-3)
    const u16* qb = Q + (bh * NTOK + min(q, NTOK - 1)) * DHEAD;
    bf16x8 qf0, qf1;
    {
        bf16x8 t0 = *(const bf16x8*)(qb + rg * 8);
        bf16x8 t1 = *(const bf16x8*)(qb + 32 + rg * 8);
#pragma unroll
        for (int i = 0; i < 8; ++i) {
            qf0[i] = (__bf16)((float)t0[i] * SCALE_QK);
            qf1[i] = (__bf16)((float)t1[i] * SCALE_QK);
        }
    }

    floatx4 oacc[4] = {};            // oacc[ct][r] = O^T[d = 16ct+4rg+r][q]
    float mi = -3.0e38f, li = 0.f;   // per-lane (per-q) softmax state
    const unsigned char* padb = pad + (size_t)b * NTOK;

    for (int jt = 0; jt < njt; ++jt) {
        int j0 = jt * 64;
        floatx4 s[4];                // s[ct][r] = S^T[key = j0+16ct+4rg+r][q]
#pragma unroll
        for (int ct = 0; ct < 4; ++ct) {
            int keyc = min(j0 + ct * 16 + lc, NTOK - 1);
            const u16* kb = Kb + (bh * NTOK + keyc) * DHEAD;
            bf16x8 kf0 = *(const bf16x8*)(kb + rg * 8);
            bf16x8 kf1 = *(const bf16x8*)(kb + 32 + rg * 8);
            floatx4 sa = {};
            sa = __builtin_amdgcn_mfma_f32_16x16x32_bf16(kf0, qf0, sa, 0, 0, 0);
            sa = __builtin_amdgcn_mfma_f32_16x16x32_bf16(kf1, qf1, sa, 0, 0, 0);
            s[ct] = sa;
        }
        // mask: this lane's keys are kb0..kb0+3 per ct (kb0 = j0+16ct+4rg)
#pragma unroll
        for (int ct = 0; ct < 4; ++ct) {
            int kb0 = j0 + ct * 16 + rg * 4;
            unsigned pw = (kb0 < NTOK) ? *(const unsigned*)(padb + kb0) : 0u;
            bool jpre = kb0 < 16;    // 4-key chunk never straddles the 16-boundary
            int tj0 = 0, rem0 = 0;
            if (!jpre) { int qj = kb0 - 16; tj0 = qj / 40; rem0 = qj - 40 * tj0; }
#pragma unroll
            for (int r = 0; r < 4; ++r) {
                int key = kb0 + r;
                bool colok = qok && (key < jend) && (((pw >> (8 * r)) & 0xFFu) != 0);
                bool ok;
                if (jpre) ok = colok;
                else {
                    int rem = rem0 + r;
                    int tj = tj0 + (rem >= 40 ? 1 : 0);
                    int remr = rem >= 40 ? rem - 40 : rem;
                    int tm = (remr >= 32) ? tmax_act : tmax_obs;
                    ok = colok && (tj <= tm);
                }
                s[ct][r] = ok ? s[ct][r] : -1.0e9f;
            }
        }
        // per-lane softmax over 16 values + cross-hi-group butterfly
        float mt = fmaxf(fmaxf(fmaxf(s[0][0], s[0][1]), fmaxf(s[0][2], s[0][3])),
                         fmaxf(fmaxf(s[1][0], s[1][1]), fmaxf(s[1][2], s[1][3])));
        float mt2 = fmaxf(fmaxf(fmaxf(s[2][0], s[2][1]), fmaxf(s[2][2], s[2][3])),
                          fmaxf(fmaxf(s[3][0], s[3][1]), fmaxf(s[3][2], s[3][3])));
        mt = fmaxf(mt, mt2);
        mt = fmaxf(mt, __shfl_xor(mt, 16));
        mt = fmaxf(mt, __shfl_xor(mt, 32));
        float mnew = fmaxf(mi, mt);
        float alpha = __expf(mi - mnew);
        float rs = 0.f;
#pragma unroll
        for (int ct = 0; ct < 4; ++ct)
#pragma unroll
            for (int r = 0; r < 4; ++r) {
                float p = __expf(s[ct][r] - mnew);
                s[ct][r] = p;
                rs += p;
            }
        rs += __shfl_xor(rs, 16);
        rs += __shfl_xor(rs, 32);
        li = li * alpha + rs;
        mi = mnew;
#pragma unroll
        for (int ct = 0; ct < 4; ++ct)
#pragma unroll
            for (int r = 0; r < 4; ++r) oacc[ct][r] *= alpha;
        // pack P row q: 4 keys per ct -> one 8B swizzled LDS write each
#pragma unroll
        for (int ct = 0; ct < 4; ++ct) {
            uint2 pk;
            pk.x = cvt_pk_bf16(s[ct][0], s[ct][1]);
            pk.y = cvt_pk_bf16(s[ct][2], s[ct][3]);
            int chunk = 2 * ct + (rg >> 1);
            int idx = lc * 64 + ((chunk ^ (lc & 7)) << 3) + ((rg & 1) << 2);
            *(uint2*)&plds[w][idx] = pk;
        }
        // PV: O^T += V^T(A) x P^T(B), two key-halves
#pragma unroll
        for (int kh = 0; kh < 2; ++kh) {
            bf16x8 pf = *(const bf16x8*)&plds[w][lc * 64 + (((4 * kh + rg) ^ (lc & 7)) << 3)];
#pragma unroll
            for (int ct = 0; ct < 4; ++ct) {
                const u16* vb = Vt + (bh * DHEAD + ct * 16 + lc) * NTOK + j0 + kh * 32;
                bf16x8 vf = *(const bf16x8*)(vb + rg * 8);
                oacc[ct] = __builtin_amdgcn_mfma_f32_16x16x32_bf16(vf, pf, oacc[ct], 0, 0, 0);
            }
        }
    }
    // epilogue: lane holds O[q][d=16ct+4rg+r]; 4 contiguous d per (ct) -> 8B stores
    if (q < NTOK) {
        float inv = 1.f / li;
#pragma unroll
        for (int ct = 0; ct < 4; ++ct) {
            uint2 pk;
            pk.x = cvt_pk_bf16(oacc[ct][0] * inv, oacc[ct][1] * inv);
            pk.y = cvt_pk_bf16(oacc[ct][2] * inv, oacc[ct][3] * inv);
            *(uint2*)&O[((size_t)b * NTOK + q) * DMODEL + h * DHEAD + ct * 16 + rg * 4] = pk;
        }
    }
}

// ---------------- launcher ----------------
extern "C" void kernel_launch(void* const* d_in, const int* in_sizes, int n_in,
                              void* d_out, int out_size, void* d_ws, size_t ws_size,
                              hipStream_t stream) {
    const float* prefix = (const float*)d_in[0];
    const float* obs    = (const float*)d_in[1];
    const float* act    = (const float*)d_in[2];
    const float* ln1_s  = (const float*)d_in[3];
    const float* ln1_b  = (const float*)d_in[4];
    const float* ln2_s  = (const float*)d_in[5];
    const float* ln2_b  = (const float*)d_in[6];
    const float* wq = (const float*)d_in[7];
    const float* wk = (const float*)d_in[8];
    const float* wv = (const float*)d_in[9];
    const float* wo = (const float*)d_in[10];
    const float* bq = (const float*)d_in[11];
    const float* bk = (const float*)d_in[12];
    const float* bv = (const float*)d_in[13];
    const float* bo = (const float*)d_in[14];
    const float* w1 = (const float*)d_in[15];
    const float* b1 = (const float*)d_in[16];
    const float* w2 = (const float*)d_in[17];
    const float* b2 = (const float*)d_in[18];
    const float* lnf_s = (const float*)d_in[19];
    const float* lnf_b = (const float*)d_in[20];
    const int* pm = (const int*)d_in[21];
    const int* om = (const int*)d_in[22];
    const int* am = (const int*)d_in[23];
    float* out = (float*)d_out;

    char* ws = (char*)d_ws;
    size_t off = 0;
    auto carve = [&](size_t bytes) -> char* {
        char* p = ws + off;
        off += (bytes + 255) & ~(size_t)255;
        return p;
    };
    float* X   = (float*)carve((size_t)BN_TOT * DMODEL * 4);
    u16*   Hb  = (u16*)carve((size_t)BN_TOT * DMODEL * 2);
    u16*   QKV = (u16*)carve((size_t)3 * BN_TOT * DMODEL * 2);  // Q | K | V^T contiguous
    u16*   Qb  = QKV;
    u16*   Kbf = QKV + (size_t)BN_TOT * DMODEL;
    u16*   Vt  = QKV + (size_t)2 * BN_TOT * DMODEL;
    u16*   Ob  = (u16*)carve((size_t)BN_TOT * DMODEL * 2);
    u16*   MID = (u16*)carve((size_t)BN_TOT * DFF * 2);
    unsigned char* PAD = (unsigned char*)carve(BN_TOT);
    float* BIASC = (float*)carve((size_t)NLAYER * 2304 * 4);
    u16*   WT  = (u16*)carve((size_t)NLAYER * 7077888 * 2);
    if (off > ws_size) return;

    const long LSTR = 7077888;
    const long OWQ = 0, OWO = 1769472, OW1 = 2359296, OW2 = 4718592;
    const long OWK = 589824, OWV = 1179648;

    dim3 blk(256);
    assemble_x<<<(BN_TOT * DMODEL + 255) / 256, blk, 0, stream>>>(prefix, obs, act, X);
    build_pad<<<(BN_TOT + 255) / 256, blk, 0, stream>>>(pm, om, am, PAD);
    build_biascat<<<(NLAYER * 2304 + 255) / 256, blk, 0, stream>>>(bq, bk, bv, BIASC);

    dim3 tb(32, 8);
    transpose_cvt<<<dim3(DMODEL / 32, DMODEL / 32, NLAYER), tb, 0, stream>>>(wq, WT + OWQ, DMODEL, DMODEL, LSTR);
    transpose_cvt<<<dim3(DMODEL / 32, DMODEL / 32, NLAYER), tb, 0, stream>>>(wk, WT + OWK, DMODEL, DMODEL, LSTR);
    transpose_cvt<<<dim3(DMODEL / 32, DMODEL / 32, NLAYER), tb, 0, stream>>>(wv, WT + OWV, DMODEL, DMODEL, LSTR);
    transpose_cvt<<<dim3(DMODEL / 32, DMODEL / 32, NLAYER), tb, 0, stream>>>(wo, WT + OWO, DMODEL, DMODEL, LSTR);
    transpose_cvt<<<dim3(DFF / 32, DMODEL / 32, NLAYER), tb, 0, stream>>>(w1, WT + OW1, DMODEL, DFF, LSTR);
    transpose_cvt<<<dim3(DMODEL / 32, DFF / 32, NLAYER), tb, 0, stream>>>(w2, WT + OW2, DFF, DMODEL, LSTR);

    dim3 g6(DMODEL / 128, BN_TOT / 128);
    dim3 gqkv(2304 / 128, BN_TOT / 128);
    dim3 g24(DFF / 128, BN_TOT / 128);
    dim3 ga(NQT * NHEAD * 8);   // 2016, XCD-grouped decode inside kernel
    dim3 gln(BN_TOT / 4);

    for (int l = 0; l < NLAYER; ++l) {
        const u16* WTl = WT + (size_t)l * LSTR;
        ln_kernel<<<gln, blk, 0, stream>>>(X, ln1_s + l * DMODEL, ln1_b + l * DMODEL, Hb, nullptr);
        gemm_k<4><<<gqkv, blk, 0, stream>>>(Hb, WTl + OWQ, BIASC + l * 2304, nullptr, Qb, BN_TOT, 2304, DMODEL);
        attn_k<<<ga, blk, 0, stream>>>(Qb, Kbf, Vt, PAD, Ob);
        gemm_k<3><<<g6, blk, 0, stream>>>(Ob, WTl + OWO, bo + l * DMODEL, X, X, BN_TOT, DMODEL, DMODEL);
        ln_kernel<<<gln, blk, 0, stream>>>(X, ln2_s + l * DMODEL, ln2_b + l * DMODEL, Hb, nullptr);
        gemm_k<2><<<g24, blk, 0, stream>>>(Hb, WTl + OW1, b1 + l * DFF, nullptr, MID, BN_TOT, DFF, DMODEL);
        gemm_k<3><<<g6, blk, 0, stream>>>(MID, WTl + OW2, b2 + l * DMODEL, X, X, BN_TOT, DMODEL, DFF);
    }
    ln_kernel<<<gln, blk, 0, stream>>>(X, lnf_s, lnf_b, nullptr, out);
}

// Round 4
// 5352.847 us; speedup vs baseline: 1.3736x; 1.1793x over previous
//
#include <hip/hip_runtime.h>

typedef unsigned short u16;
typedef __attribute__((ext_vector_type(8))) __bf16 bf16x8;
typedef __attribute__((ext_vector_type(4))) float floatx4;

#define NTOK 1296      // P + H*(NO+NA) = 16 + 32*40
#define BN_TOT 10368   // B * NTOK
#define DMODEL 768
#define DFF 3072
#define NHEAD 12
#define DHEAD 64
#define NLAYER 12
#define NQT 21         // ceil(NTOK/64)
#define SCALE_QK 0.125f  // 1/sqrt(64)

__device__ __forceinline__ u16 f2bf(float f) {
    unsigned u = __builtin_bit_cast(unsigned, f);
    unsigned r = (u + 0x7FFFu + ((u >> 16) & 1u)) >> 16;
    return (u16)r;
}

__device__ __forceinline__ unsigned cvt_pk_bf16(float lo, float hi) {
    unsigned r;
    asm("v_cvt_pk_bf16_f32 %0, %1, %2" : "=v"(r) : "v"(lo), "v"(hi));
    return r;
}

__device__ __forceinline__ float gelu_f(float x) {
    float u = 0.7978845608028654f * (x + 0.044715f * x * x * x);
    float t = 1.f - 2.f / (__expf(2.f * u) + 1.f);   // tanh(u)
    return 0.5f * x * (1.f + t);
}

// ---------------- input assembly ----------------
__global__ void assemble_x(const float* __restrict__ prefix,
                           const float* __restrict__ obs,
                           const float* __restrict__ act,
                           float* __restrict__ X) {
    int idx = blockIdx.x * 256 + threadIdx.x;
    if (idx >= BN_TOT * DMODEL) return;
    int d = idx % DMODEL;
    int n = (idx / DMODEL) % NTOK;
    int b = idx / (DMODEL * NTOK);
    float v;
    if (n < 16) {
        v = prefix[((size_t)b * 16 + n) * DMODEL + d];
    } else {
        int q = n - 16;
        int m = q / 40, r = q % 40;
        if (r < 32) v = obs[(((size_t)b * 32 + m) * 32 + r) * DMODEL + d];
        else        v = act[(((size_t)b * 32 + m) * 8 + (r - 32)) * DMODEL + d];
    }
    X[idx] = v;
}

__global__ void build_pad(const int* __restrict__ pm,
                          const int* __restrict__ om,
                          const int* __restrict__ am,
                          unsigned char* __restrict__ pad) {
    int idx = blockIdx.x * 256 + threadIdx.x;
    if (idx >= BN_TOT) return;
    int n = idx % NTOK, b = idx / NTOK;
    int v;
    if (n < 16) v = pm[b * 16 + n];
    else {
        int q = n - 16;
        int m = q / 40, r = q % 40;
        v = (r < 32) ? om[(b * 32 + m) * 32 + r] : am[(b * 32 + m) * 8 + (r - 32)];
    }
    pad[idx] = (v != 0) ? 1 : 0;
}

__global__ void build_biascat(const float* __restrict__ bq,
                              const float* __restrict__ bk,
                              const float* __restrict__ bv,
                              float* __restrict__ bc) {
    int idx = blockIdx.x * 256 + threadIdx.x;
    if (idx >= NLAYER * 2304) return;
    int l = idx / 2304, c = idx % 2304;
    int which = c / 768, cc = c % 768;
    const float* src = (which == 0) ? bq : (which == 1) ? bk : bv;
    bc[idx] = src[l * 768 + cc];
}

// ---------------- weight transpose + cvt: W fp32 [K][Nc] -> bf16 [Nc][K] ----------------
__global__ void transpose_cvt(const float* __restrict__ src, u16* __restrict__ dst,
                              int K, int Nc, long layerStride) {
    src += (size_t)blockIdx.z * K * Nc;
    dst += (size_t)blockIdx.z * layerStride;
    __shared__ float tile[32][33];
    int n0 = blockIdx.x * 32, k0 = blockIdx.y * 32;
    int tx = threadIdx.x, ty = threadIdx.y;
#pragma unroll
    for (int i = 0; i < 4; ++i)
        tile[ty + i * 8][tx] = src[(size_t)(k0 + ty + i * 8) * Nc + n0 + tx];
    __syncthreads();
#pragma unroll
    for (int i = 0; i < 4; ++i) {
        int n = n0 + ty + i * 8;
        dst[(size_t)n * K + k0 + tx] = f2bf(tile[tx][ty + i * 8]);
    }
}

// ---------------- LayerNorm: one wave per row, no barriers ----------------
__global__ __launch_bounds__(256) void ln_kernel(const float* __restrict__ x,
                                                 const float* __restrict__ s,
                                                 const float* __restrict__ bb,
                                                 u16* __restrict__ obf,
                                                 float* __restrict__ of32) {
    int row = blockIdx.x * 4 + (threadIdx.x >> 6);
    int lane = threadIdx.x & 63;
    const float4* xv = (const float4*)(x + (size_t)row * DMODEL);
    float4 v[3];
    v[0] = xv[lane]; v[1] = xv[lane + 64]; v[2] = xv[lane + 128];
    float sum = 0.f, sq = 0.f;
#pragma unroll
    for (int i = 0; i < 3; ++i) {
        sum += v[i].x + v[i].y + v[i].z + v[i].w;
        sq  += v[i].x * v[i].x + v[i].y * v[i].y + v[i].z * v[i].z + v[i].w * v[i].w;
    }
#pragma unroll
    for (int d = 32; d > 0; d >>= 1) {
        sum += __shfl_xor(sum, d);
        sq  += __shfl_xor(sq, d);
    }
    float mu = sum * (1.f / DMODEL);
    float var = sq * (1.f / DMODEL) - mu * mu;
    float rstd = rsqrtf(var + 1e-6f);
    const float4* sv = (const float4*)s;
    const float4* bv = (const float4*)bb;
#pragma unroll
    for (int i = 0; i < 3; ++i) {
        float4 sc = sv[lane + i * 64], bc = bv[lane + i * 64];
        float y0 = (v[i].x - mu) * rstd * sc.x + bc.x;
        float y1 = (v[i].y - mu) * rstd * sc.y + bc.y;
        float y2 = (v[i].z - mu) * rstd * sc.z + bc.z;
        float y3 = (v[i].w - mu) * rstd * sc.w + bc.w;
        size_t base = (size_t)row * DMODEL + i * 256 + lane * 4;
        if (obf) {
            uint2 pk;
            pk.x = (unsigned)f2bf(y0) | ((unsigned)f2bf(y1) << 16);
            pk.y = (unsigned)f2bf(y2) | ((unsigned)f2bf(y3) << 16);
            *(uint2*)&obf[base] = pk;
        } else {
            float4 o = {y0, y1, y2, y3};
            *(float4*)&of32[base] = o;
        }
    }
}

// ---------------- GEMM with global_load_lds staging + XOR-swizzled LDS ----------------
template <int EPI>
__global__ __launch_bounds__(256) void gemm_k(const u16* __restrict__ A,
                                              const u16* __restrict__ Bt,
                                              const float* __restrict__ bias,
                                              const float* __restrict__ resid,
                                              void* __restrict__ outp,
                                              int M, int Nc, int K) {
    __shared__ __attribute__((aligned(16))) u16 As[4096];  // 512 slots x 16B
    __shared__ __attribute__((aligned(16))) u16 Bs[4096];
    int tid = threadIdx.x;
    int bc = blockIdx.x, br = blockIdx.y;
    int lane = tid & 63, w = tid >> 6;
    int wr = (w >> 1) * 64, wc = (w & 1) * 64;
    int lr = lane & 15, C = lane >> 4;
    floatx4 acc[4][4] = {};

    int r0 = tid >> 2;       // staging row within 64-row half (0..63)
    int cph = tid & 3;       // physical 16B chunk slot within row
    const u16* Abase = A + (size_t)(br * 128) * K;
    const u16* Bbase = Bt + (size_t)(bc * 128) * K;

    for (int k0 = 0; k0 < K; k0 += 32) {
        __syncthreads();
#pragma unroll
        for (int i = 0; i < 2; ++i) {
            int r = i * 64 + r0;
            int cl = cph ^ ((r >> 1) & 3);
            const u16* ga = Abase + (size_t)r * K + k0 + cl * 8;
            const u16* gb = Bbase + (size_t)r * K + k0 + cl * 8;
            __builtin_amdgcn_global_load_lds(
                (const __attribute__((address_space(1))) void*)ga,
                (__attribute__((address_space(3))) void*)&As[(i * 256 + w * 64) * 8], 16, 0, 0);
            __builtin_amdgcn_global_load_lds(
                (const __attribute__((address_space(1))) void*)gb,
                (__attribute__((address_space(3))) void*)&Bs[(i * 256 + w * 64) * 8], 16, 0, 0);
        }
        __syncthreads();
        bf16x8 af[4], bf[4];
#pragma unroll
        for (int i = 0; i < 4; ++i) {
            int R = wr + i * 16 + lr;
            af[i] = *(const bf16x8*)&As[(R * 4 + (C ^ ((R >> 1) & 3))) * 8];
        }
#pragma unroll
        for (int i = 0; i < 4; ++i) {
            int R = wc + i * 16 + lr;
            bf[i] = *(const bf16x8*)&Bs[(R * 4 + (C ^ ((R >> 1) & 3))) * 8];
        }
#pragma unroll
        for (int i = 0; i < 4; ++i)
#pragma unroll
            for (int j = 0; j < 4; ++j)
                acc[i][j] = __builtin_amdgcn_mfma_f32_16x16x32_bf16(af[i], bf[j], acc[i][j], 0, 0, 0);
    }

    int gr0 = br * 128 + wr, gc0 = bc * 128 + wc;
#pragma unroll
    for (int i = 0; i < 4; ++i) {
#pragma unroll
        for (int j = 0; j < 4; ++j) {
#pragma unroll
            for (int r = 0; r < 4; ++r) {
                int grow = gr0 + i * 16 + (lane >> 4) * 4 + r;
                int gcol = gc0 + j * 16 + lr;
                float v = acc[i][j][r] + bias[gcol];
                if constexpr (EPI == 2) {
                    ((u16*)outp)[(size_t)grow * Nc + gcol] = f2bf(gelu_f(v));
                } else if constexpr (EPI == 3) {
                    size_t idx = (size_t)grow * Nc + gcol;
                    ((float*)outp)[idx] = resid[idx] + v;
                } else {  // EPI == 4: fused QKV epilogue; outp = Qb (K,V at fixed offsets)
                    int b = grow / NTOK, n = grow % NTOK;
                    int which = gcol / 768;
                    int c = gcol - which * 768;
                    int nh = c >> 6, dh = c & 63;
                    u16* base = (u16*)outp + (size_t)which * ((size_t)BN_TOT * DMODEL);
                    if (which < 2)
                        base[(((size_t)b * NHEAD + nh) * NTOK + n) * DHEAD + dh] = f2bf(v);
                    else
                        base[(((size_t)b * NHEAD + nh) * DHEAD + dh) * NTOK + n] = f2bf(v);
                }
            }
        }
    }
}

// ---------------- fused attention: block-cooperative K/V LDS staging (2-phase
// double-buffer, pre-swizzled gload_lds source), swapped-operand S^T, per-lane
// softmax, setprio MFMA clusters, XCD-grouped + longest-first ----------------
__global__ __launch_bounds__(256) void attn_k(const u16* __restrict__ Q,
                                              const u16* __restrict__ Kb,
                                              const u16* __restrict__ Vt,
                                              const unsigned char* __restrict__ pad,
                                              u16* __restrict__ O) {
    // K/V tiles 64x64 bf16, chunk(16B)-XOR swizzle: physical chunk cp of row r
    // holds logical chunk cp^(r&7)  (involution on both staging-src and read)
    __shared__ __attribute__((aligned(16))) u16 Ks[2][64 * 64];
    __shared__ __attribute__((aligned(16))) u16 Vs[2][64 * 64];
    __shared__ __attribute__((aligned(16))) u16 plds[4][16 * 64];

    int wgid = blockIdx.x;
    int xcd = wgid & 7, slot = wgid >> 3;
    int qt = NQT - 1 - (slot % NQT);          // longest q-tiles dispatch first
    int g = (slot / NQT) * 8 + xcd;           // all 21 tiles of (b,h) on one XCD
    int b = g / NHEAD, h = g % NHEAD;

    int tid = threadIdx.x, lane = tid & 63, w = tid >> 6;
    int rg = lane >> 4, lc = lane & 15;
    int q0 = qt * 64 + w * 16;
    size_t bh = (size_t)(b * NHEAD + h);

    int lastrow = min(qt * 64 + 63, NTOK - 1);
    int jend = (lastrow < 16) ? 16 : 16 + 40 * ((lastrow - 16) / 40 + 1);
    jend = min(jend, NTOK);
    int njt = (jend + 63) >> 6;

    int q = q0 + lc;                 // this lane's query row (col of S^T)
    bool qok = q < NTOK;
    int tmax_obs = -1, tmax_act = -1;
    if (qok && q >= 16) {
        int qi = q - 16;
        int ti = qi / 40;
        bool gact = (qi % 40) >= 32;
        tmax_obs = ti;
        tmax_act = gact ? ti : -1;
    }

    // Q fragment (B operand), 1/sqrt(DH) pre-folded (exact *2^-3)
    const u16* qb = Q + (bh * NTOK + min(q, NTOK - 1)) * DHEAD;
    bf16x8 qf0, qf1;
    {
        bf16x8 t0 = *(const bf16x8*)(qb + rg * 8);
        bf16x8 t1 = *(const bf16x8*)(qb + 32 + rg * 8);
#pragma unroll
        for (int i = 0; i < 8; ++i) {
            qf0[i] = (__bf16)((float)t0[i] * SCALE_QK);
            qf1[i] = (__bf16)((float)t1[i] * SCALE_QK);
        }
    }

    // cooperative staging: 512 chunks x 16B per matrix; thread covers chunks
    // {tid, tid+256}; dest linear, source pre-swizzled (rule #21)
    auto stage = [&](int buf, int jt) {
#pragma unroll
        for (int i = 0; i < 2; ++i) {
            int r = i * 32 + (tid >> 3);             // tile row 0..63
            int cl = (tid & 7) ^ (r & 7);            // logical chunk fetched
            const u16* gk = Kb + (bh * NTOK + min(jt * 64 + r, NTOK - 1)) * DHEAD + cl * 8;
            const u16* gv = Vt + (bh * DHEAD + r) * NTOK + jt * 64 + cl * 8;
            __builtin_amdgcn_global_load_lds(
                (const __attribute__((address_space(1))) void*)gk,
                (__attribute__((address_space(3))) void*)&Ks[buf][(i * 256 + w * 64) * 8], 16, 0, 0);
            __builtin_amdgcn_global_load_lds(
                (const __attribute__((address_space(1))) void*)gv,
                (__attribute__((address_space(3))) void*)&Vs[buf][(i * 256 + w * 64) * 8], 16, 0, 0);
        }
    };

    floatx4 oacc[4] = {};            // oacc[ct][r] = O^T[d = 16ct+4rg+r][q]
    float mi = -3.0e38f, li = 0.f;   // per-lane (per-q) softmax state
    const unsigned char* padb = pad + (size_t)b * NTOK;

    stage(0, 0);
    __syncthreads();
    int cur = 0;

    for (int jt = 0; jt < njt; ++jt) {
        int j0 = jt * 64;
        if (jt + 1 < njt) stage(cur ^ 1, jt + 1);   // prefetch next tile

        floatx4 s[4];                // s[ct][r] = S^T[key = j0+16ct+4rg+r][q]
        __builtin_amdgcn_s_setprio(1);
#pragma unroll
        for (int ct = 0; ct < 4; ++ct) {
            int kk = ct * 16 + lc;   // key row within tile
            bf16x8 kf0 = *(const bf16x8*)&Ks[cur][kk * 64 + ((rg ^ (lc & 7)) << 3)];
            bf16x8 kf1 = *(const bf16x8*)&Ks[cur][kk * 64 + (((4 + rg) ^ (lc & 7)) << 3)];
            floatx4 sa = {};
            sa = __builtin_amdgcn_mfma_f32_16x16x32_bf16(kf0, qf0, sa, 0, 0, 0);
            sa = __builtin_amdgcn_mfma_f32_16x16x32_bf16(kf1, qf1, sa, 0, 0, 0);
            s[ct] = sa;
        }
        __builtin_amdgcn_s_setprio(0);

        // mask: this lane's keys are kb0..kb0+3 per ct (kb0 = j0+16ct+4rg)
#pragma unroll
        for (int ct = 0; ct < 4; ++ct) {
            int kb0 = j0 + ct * 16 + rg * 4;
            unsigned pw = (kb0 < NTOK) ? *(const unsigned*)(padb + kb0) : 0u;
            bool jpre = kb0 < 16;    // 4-key chunk never straddles the 16-boundary
            int tj0 = 0, rem0 = 0;
            if (!jpre) { int qj = kb0 - 16; tj0 = qj / 40; rem0 = qj - 40 * tj0; }
#pragma unroll
            for (int r = 0; r < 4; ++r) {
                int key = kb0 + r;
                bool colok = qok && (key < jend) && (((pw >> (8 * r)) & 0xFFu) != 0);
                bool ok;
                if (jpre) ok = colok;
                else {
                    int rem = rem0 + r;
                    int tj = tj0 + (rem >= 40 ? 1 : 0);
                    int remr = rem >= 40 ? rem - 40 : rem;
                    int tm = (remr >= 32) ? tmax_act : tmax_obs;
                    ok = colok && (tj <= tm);
                }
                s[ct][r] = ok ? s[ct][r] : -1.0e9f;
            }
        }
        // per-lane softmax over 16 values + cross-hi-group butterfly
        float mt = fmaxf(fmaxf(fmaxf(s[0][0], s[0][1]), fmaxf(s[0][2], s[0][3])),
                         fmaxf(fmaxf(s[1][0], s[1][1]), fmaxf(s[1][2], s[1][3])));
        float mt2 = fmaxf(fmaxf(fmaxf(s[2][0], s[2][1]), fmaxf(s[2][2], s[2][3])),
                          fmaxf(fmaxf(s[3][0], s[3][1]), fmaxf(s[3][2], s[3][3])));
        mt = fmaxf(mt, mt2);
        mt = fmaxf(mt, __shfl_xor(mt, 16));
        mt = fmaxf(mt, __shfl_xor(mt, 32));
        float mnew = fmaxf(mi, mt);
        float alpha = __expf(mi - mnew);
        float rs = 0.f;
#pragma unroll
        for (int ct = 0; ct < 4; ++ct)
#pragma unroll
            for (int r = 0; r < 4; ++r) {
                float p = __expf(s[ct][r] - mnew);
                s[ct][r] = p;
                rs += p;
            }
        rs += __shfl_xor(rs, 16);
        rs += __shfl_xor(rs, 32);
        li = li * alpha + rs;
        mi = mnew;
#pragma unroll
        for (int ct = 0; ct < 4; ++ct)
#pragma unroll
            for (int r = 0; r < 4; ++r) oacc[ct][r] *= alpha;

        // pack P row q: 4 keys per ct -> one 8B swizzled LDS write each
#pragma unroll
        for (int ct = 0; ct < 4; ++ct) {
            uint2 pk;
            pk.x = cvt_pk_bf16(s[ct][0], s[ct][1]);
            pk.y = cvt_pk_bf16(s[ct][2], s[ct][3]);
            int chunk = 2 * ct + (rg >> 1);
            int idx = lc * 64 + ((chunk ^ (lc & 7)) << 3) + ((rg & 1) << 2);
            *(uint2*)&plds[w][idx] = pk;
        }
        // PV: O^T += V^T(A) x P^T(B), two key-halves; V from swizzled LDS
        __builtin_amdgcn_s_setprio(1);
#pragma unroll
        for (int kh = 0; kh < 2; ++kh) {
            bf16x8 pf = *(const bf16x8*)&plds[w][lc * 64 + (((4 * kh + rg) ^ (lc & 7)) << 3)];
#pragma unroll
            for (int ct = 0; ct < 4; ++ct) {
                int dd = ct * 16 + lc;   // d row within tile
                bf16x8 vf = *(const bf16x8*)&Vs[cur][dd * 64 + (((kh * 4 + rg) ^ (lc & 7)) << 3)];
                oacc[ct] = __builtin_amdgcn_mfma_f32_16x16x32_bf16(vf, pf, oacc[ct], 0, 0, 0);
            }
        }
        __builtin_amdgcn_s_setprio(0);

        __syncthreads();             // drains prefetch; all warps done with cur
        cur ^= 1;
    }

    // epilogue: lane holds O[q][d=16ct+4rg+r]; 4 contiguous d per (ct) -> 8B stores
    if (q < NTOK) {
        float inv = 1.f / li;
#pragma unroll
        for (int ct = 0; ct < 4; ++ct) {
            uint2 pk;
            pk.x = cvt_pk_bf16(oacc[ct][0] * inv, oacc[ct][1] * inv);
            pk.y = cvt_pk_bf16(oacc[ct][2] * inv, oacc[ct][3] * inv);
            *(uint2*)&O[((size_t)b * NTOK + q) * DMODEL + h * DHEAD + ct * 16 + rg * 4] = pk;
        }
    }
}

// ---------------- launcher ----------------
extern "C" void kernel_launch(void* const* d_in, const int* in_sizes, int n_in,
                              void* d_out, int out_size, void* d_ws, size_t ws_size,
                              hipStream_t stream) {
    const float* prefix = (const float*)d_in[0];
    const float* obs    = (const float*)d_in[1];
    const float* act    = (const float*)d_in[2];
    const float* ln1_s  = (const float*)d_in[3];
    const float* ln1_b  = (const float*)d_in[4];
    const float* ln2_s  = (const float*)d_in[5];
    const float* ln2_b  = (const float*)d_in[6];
    const float* wq = (const float*)d_in[7];
    const float* wk = (const float*)d_in[8];
    const float* wv = (const float*)d_in[9];
    const float* wo = (const float*)d_in[10];
    const float* bq = (const float*)d_in[11];
    const float* bk = (const float*)d_in[12];
    const float* bv = (const float*)d_in[13];
    const float* bo = (const float*)d_in[14];
    const float* w1 = (const float*)d_in[15];
    const float* b1 = (const float*)d_in[16];
    const float* w2 = (const float*)d_in[17];
    const float* b2 = (const float*)d_in[18];
    const float* lnf_s = (const float*)d_in[19];
    const float* lnf_b = (const float*)d_in[20];
    const int* pm = (const int*)d_in[21];
    const int* om = (const int*)d_in[22];
    const int* am = (const int*)d_in[23];
    float* out = (float*)d_out;

    char* ws = (char*)d_ws;
    size_t off = 0;
    auto carve = [&](size_t bytes) -> char* {
        char* p = ws + off;
        off += (bytes + 255) & ~(size_t)255;
        return p;
    };
    float* X   = (float*)carve((size_t)BN_TOT * DMODEL * 4);
    u16*   Hb  = (u16*)carve((size_t)BN_TOT * DMODEL * 2);
    u16*   QKV = (u16*)carve((size_t)3 * BN_TOT * DMODEL * 2);  // Q | K | V^T contiguous
    u16*   Qb  = QKV;
    u16*   Kbf = QKV + (size_t)BN_TOT * DMODEL;
    u16*   Vt  = QKV + (size_t)2 * BN_TOT * DMODEL;
    u16*   Ob  = (u16*)carve((size_t)BN_TOT * DMODEL * 2);
    u16*   MID = (u16*)carve((size_t)BN_TOT * DFF * 2);
    unsigned char* PAD = (unsigned char*)carve(BN_TOT);
    float* BIASC = (float*)carve((size_t)NLAYER * 2304 * 4);
    u16*   WT  = (u16*)carve((size_t)NLAYER * 7077888 * 2);
    if (off > ws_size) return;

    const long LSTR = 7077888;
    const long OWQ = 0, OWO = 1769472, OW1 = 2359296, OW2 = 4718592;
    const long OWK = 589824, OWV = 1179648;

    dim3 blk(256);
    assemble_x<<<(BN_TOT * DMODEL + 255) / 256, blk, 0, stream>>>(prefix, obs, act, X);
    build_pad<<<(BN_TOT + 255) / 256, blk, 0, stream>>>(pm, om, am, PAD);
    build_biascat<<<(NLAYER * 2304 + 255) / 256, blk, 0, stream>>>(bq, bk, bv, BIASC);

    dim3 tb(32, 8);
    transpose_cvt<<<dim3(DMODEL / 32, DMODEL / 32, NLAYER), tb, 0, stream>>>(wq, WT + OWQ, DMODEL, DMODEL, LSTR);
    transpose_cvt<<<dim3(DMODEL / 32, DMODEL / 32, NLAYER), tb, 0, stream>>>(wk, WT + OWK, DMODEL, DMODEL, LSTR);
    transpose_cvt<<<dim3(DMODEL / 32, DMODEL / 32, NLAYER), tb, 0, stream>>>(wv, WT + OWV, DMODEL, DMODEL, LSTR);
    transpose_cvt<<<dim3(DMODEL / 32, DMODEL / 32, NLAYER), tb, 0, stream>>>(wo, WT + OWO, DMODEL, DMODEL, LSTR);
    transpose_cvt<<<dim3(DFF / 32, DMODEL / 32, NLAYER), tb, 0, stream>>>(w1, WT + OW1, DMODEL, DFF, LSTR);
    transpose_cvt<<<dim3(DMODEL / 32, DFF / 32, NLAYER), tb, 0, stream>>>(w2, WT + OW2, DFF, DMODEL, LSTR);

    dim3 g6(DMODEL / 128, BN_TOT / 128);
    dim3 gqkv(2304 / 128, BN_TOT / 128);
    dim3 g24(DFF / 128, BN_TOT / 128);
    dim3 ga(NQT * NHEAD * 8);   // 2016, XCD-grouped decode inside kernel
    dim3 gln(BN_TOT / 4);

    for (int l = 0; l < NLAYER; ++l) {
        const u16* WTl = WT + (size_t)l * LSTR;
        ln_kernel<<<gln, blk, 0, stream>>>(X, ln1_s + l * DMODEL, ln1_b + l * DMODEL, Hb, nullptr);
        gemm_k<4><<<gqkv, blk, 0, stream>>>(Hb, WTl + OWQ, BIASC + l * 2304, nullptr, Qb, BN_TOT, 2304, DMODEL);
        attn_k<<<ga, blk, 0, stream>>>(Qb, Kbf, Vt, PAD, Ob);
        gemm_k<3><<<g6, blk, 0, stream>>>(Ob, WTl + OWO, bo + l * DMODEL, X, X, BN_TOT, DMODEL, DMODEL);
        ln_kernel<<<gln, blk, 0, stream>>>(X, ln2_s + l * DMODEL, ln2_b + l * DMODEL, Hb, nullptr);
        gemm_k<2><<<g24, blk, 0, stream>>>(Hb, WTl + OW1, b1 + l * DFF, nullptr, MID, BN_TOT, DFF, DMODEL);
        gemm_k<3><<<g6, blk, 0, stream>>>(MID, WTl + OW2, b2 + l * DMODEL, X, X, BN_TOT, DMODEL, DFF);
    }
    ln_kernel<<<gln, blk, 0, stream>>>(X, lnf_s, lnf_b, nullptr, out);
}